// Round 14
// baseline (269.771 us; speedup 1.0000x reference)
//
#include <hip/hip_runtime.h>

#define N_NODES 100000
#define N_EDGES 1600000
#define N_LABEL 200000
#define HID 128
#define OUT 5

#define BSH   7                       // bucket shift: 128 nodes per bucket
#define BSZ   128                     // nodes per bucket
#define NBUCK 782                     // ceil(N_NODES/128)
#define EPB   2048                    // edges per partition block
#define NBLK_E 782                    // ceil(N_EDGES/EPB)
#define PREC_BLKS 9                   // ceil(129*16/256)

// ---------------------------------------------------------------------------
// Linear network: out[l] = proj[d][0..4] + proj[p][5..9] + b_lin,
//   t[n]    = dinv_n * (x[n] @ G)            (fp32, 16-col padded, 64B row)
//   proj[n] = dinv_n * (sum_{src} t[src] + t[n]) + c0
// with G = W_gcn @ [W_lin_top | W_lin_bot] (128x10), c0 = b_gcn @ W2.
// Aggregation is EDGE-PARALLEL per 128-node bucket with LDS fp32 atomics:
// no CSR, no per-node loop, no divergence.
// ---------------------------------------------------------------------------

// K_hist (+ merged precomp): blocks < NBLK_E histogram dst buckets;
// blocks >= NBLK_E compute G (row 128 = c0).
__global__ __launch_bounds__(256) void k_hist(const int* __restrict__ ei,
                                              int* __restrict__ hist,
                                              const float* __restrict__ Wg,
                                              const float* __restrict__ bg,
                                              const float* __restrict__ Wl,
                                              float* __restrict__ G) {
    const int t = threadIdx.x, b = blockIdx.x;
    if (b >= NBLK_E) {   // precomp path
        int o = (b - NBLK_E) * 256 + t;
        if (o < 129 * 16) {
            int r = o >> 4, jj = o & 15;
            float acc = 0.f;
            if (jj < 2 * OUT) {
                const int half = (jj >= OUT);
                const int j = half ? jj - OUT : jj;
                for (int c = 0; c < HID; ++c) {
                    float w2 = Wl[(half * HID + c) * OUT + j];
                    float a = (r < HID) ? Wg[r * HID + c] : bg[c];
                    acc += a * w2;
                }
            }
            G[o] = acc;
        }
        return;
    }
    __shared__ int h[NBUCK];
    for (int i = t; i < NBUCK; i += 256) h[i] = 0;
    __syncthreads();
    const int e0 = b * EPB;
#pragma unroll
    for (int i = 0; i < 8; ++i) {
        int e = e0 + i * 256 + t;
        if (e < N_EDGES) atomicAdd(&h[ei[N_EDGES + e] >> BSH], 1);
    }
    __syncthreads();
    for (int i = t; i < NBUCK; i += 256) hist[i * NBLK_E + b] = h[i];
}

// K_scanb: per-bucket scan over 782 block entries + atomic-ticket bucket base.
__global__ __launch_bounds__(256) void k_scanb(int* __restrict__ hist,
                                               int* __restrict__ btot,
                                               int* __restrict__ bbase,
                                               int* __restrict__ total) {
    __shared__ int part[256];
    const int b = blockIdx.x, t = threadIdx.x;
    int* row = hist + b * NBLK_E;
    const int lo = t * 4, hi = min(lo + 4, NBLK_E);
    int v[4]; int s = 0;
    for (int i = lo; i < hi; ++i) { v[i - lo] = row[i]; s += v[i - lo]; }
    part[t] = s;
    __syncthreads();
#pragma unroll
    for (int off = 1; off < 256; off <<= 1) {
        int a = (t >= off) ? part[t - off] : 0;
        __syncthreads();
        part[t] += a;
        __syncthreads();
    }
    int run = part[t] - s;
    for (int i = lo; i < hi; ++i) { int x = v[i - lo]; row[i] = run; run += x; }
    if (t == 255) {
        int tot = part[255];
        btot[b] = tot;
        bbase[b] = atomicAdd(total, tot);   // disjoint range ticket
    }
}

// K_part: scatter edges into bucket regions. bedge = src | (dst&127)<<20.
__global__ __launch_bounds__(256) void k_part(const int* __restrict__ ei,
                                              const int* __restrict__ hist,
                                              const int* __restrict__ bbase,
                                              unsigned* __restrict__ bedge) {
    __shared__ int cur[NBUCK];
    const int t = threadIdx.x, b = blockIdx.x;
    for (int i = t; i < NBUCK; i += 256) cur[i] = bbase[i] + hist[i * NBLK_E + b];
    __syncthreads();
    const int e0 = b * EPB;
#pragma unroll
    for (int i = 0; i < 8; ++i) {
        int e = e0 + i * 256 + t;
        if (e < N_EDGES) {
            int dst = ei[N_EDGES + e];
            unsigned src = (unsigned)ei[e];
            int pos = atomicAdd(&cur[dst >> BSH], 1);
            bedge[pos] = src | ((unsigned)(dst & (BSZ - 1)) << 20);
        }
    }
}

// K_deg: per-bucket degree count -> dinv (needed before k_t).
__global__ __launch_bounds__(256) void k_deg(const unsigned* __restrict__ bedge,
                                             const int* __restrict__ bbase,
                                             const int* __restrict__ btot,
                                             float* __restrict__ dinv) {
    __shared__ int cnt[BSZ];
    const int b = blockIdx.x, t = threadIdx.x;
    const int base = bbase[b], size = btot[b];
    if (t < BSZ) cnt[t] = 0;
    __syncthreads();
    for (int e = t; e < size; e += 256) atomicAdd(&cnt[bedge[base + e] >> 20], 1);
    __syncthreads();
    if (t < BSZ) {
        int n = b * BSZ + t;
        if (n < N_NODES) dinv[n] = rsqrtf((float)(cnt[t] + 1));
    }
}

// K_t: t[n][0..9] = dinv[n] * (x[n] @ G), rows padded to 16 (cols 10-15 = 0).
__global__ __launch_bounds__(256) void k_t(const float* __restrict__ x,
                                           const float* __restrict__ G,
                                           const float* __restrict__ dinv,
                                           float* __restrict__ t) {
    __shared__ float Gs[HID * 11];
    const int tid = threadIdx.x;
    for (int o = tid; o < HID * 10; o += 256) {
        int k = o / 10, j = o - k * 10;
        Gs[k * 11 + j] = G[k * 16 + j];
    }
    __syncthreads();

    int gid = blockIdx.x * 256 + tid;
    int n = gid >> 4;
    int i = gid & 15;

    float xv[8];
#pragma unroll
    for (int m = 0; m < 8; ++m) xv[m] = x[(size_t)n * HID + i + 16 * m];

    float p[10];
#pragma unroll
    for (int j = 0; j < 10; ++j) p[j] = 0.f;
#pragma unroll
    for (int m = 0; m < 8; ++m) {
        const float* g = &Gs[(i + 16 * m) * 11];
#pragma unroll
        for (int j = 0; j < 10; ++j) p[j] += xv[m] * g[j];
    }
#pragma unroll
    for (int off = 1; off < 16; off <<= 1) {
#pragma unroll
        for (int j = 0; j < 10; ++j) p[j] += __shfl_xor(p[j], off);
    }
    float val = (i == 0) ? p[0] : (i == 1) ? p[1] : (i == 2) ? p[2] : (i == 3) ? p[3] :
                (i == 4) ? p[4] : (i == 5) ? p[5] : (i == 6) ? p[6] : (i == 7) ? p[7] :
                (i == 8) ? p[8] : (i == 9) ? p[9] : 0.f;
    t[(size_t)n * 16 + i] = dinv[n] * val;
}

// ---------------------------------------------------------------------------
// K_accum: EDGE-PARALLEL aggregation per bucket. acc[128][17] fp32 in LDS,
//     init = t[n] (self term). 16 groups x 16 lanes; per edge: uniform bedge
//     word, one 64B t-row gather, 16 ds_add_f32. Final: proj = dinv*acc + c0.
// ---------------------------------------------------------------------------
__global__ __launch_bounds__(256) void k_accum(const unsigned* __restrict__ bedge,
                                               const int* __restrict__ bbase,
                                               const int* __restrict__ btot,
                                               const float* __restrict__ t,
                                               const float* __restrict__ dinv,
                                               const float* __restrict__ G,
                                               float* __restrict__ proj) {
    __shared__ float acc[BSZ][17];
    const int b = blockIdx.x, tid = threadIdx.x;
    const int base = bbase[b], size = btot[b];
    const int g = tid >> 4;     // group 0..15
    const int i = tid & 15;     // float within row

    // init with self term
    for (int r = g; r < BSZ; r += 16) {
        int n = b * BSZ + r;
        acc[r][i] = (n < N_NODES) ? t[(size_t)n * 16 + i] : 0.f;
    }
    __syncthreads();

    int e = 0;
    for (; e + 64 <= size; e += 64) {   // 16 groups x 4 edges per iter
        unsigned w0 = bedge[base + e + g];
        unsigned w1 = bedge[base + e + 16 + g];
        unsigned w2 = bedge[base + e + 32 + g];
        unsigned w3 = bedge[base + e + 48 + g];
        float v0 = t[(size_t)(w0 & 0xFFFFFu) * 16 + i];
        float v1 = t[(size_t)(w1 & 0xFFFFFu) * 16 + i];
        float v2 = t[(size_t)(w2 & 0xFFFFFu) * 16 + i];
        float v3 = t[(size_t)(w3 & 0xFFFFFu) * 16 + i];
        atomicAdd(&acc[w0 >> 20][i], v0);
        atomicAdd(&acc[w1 >> 20][i], v1);
        atomicAdd(&acc[w2 >> 20][i], v2);
        atomicAdd(&acc[w3 >> 20][i], v3);
    }
    for (int e2 = e + g; e2 < size; e2 += 16) {
        unsigned w = bedge[base + e2];
        float v = t[(size_t)(w & 0xFFFFFu) * 16 + i];
        atomicAdd(&acc[w >> 20][i], v);
    }
    __syncthreads();

    const float c0 = G[HID * 16 + i];
    for (int r = g; r < BSZ; r += 16) {
        int n = b * BSZ + r;
        if (n < N_NODES) proj[(size_t)n * 16 + i] = dinv[n] * acc[r][i] + c0;
    }
}

// K_link: out[l][o] = proj[d][o] + proj[p][5+o] + b_lin[o]
__global__ __launch_bounds__(256) void k_link2(const int* __restrict__ eli,
                                               const float* __restrict__ proj,
                                               const float* __restrict__ bl,
                                               float* __restrict__ out) {
    int t = blockIdx.x * 256 + threadIdx.x;
    int l = t >> 3, o = t & 7;
    if (l >= N_LABEL || o >= OUT) return;
    int d = eli[l];
    int p = eli[N_LABEL + l];
    out[l * OUT + o] = proj[d * 16 + o] + proj[p * 16 + OUT + o] + bl[o];
}

// ---------------------------------------------------------------------------
extern "C" void kernel_launch(void* const* d_in, const int* in_sizes, int n_in,
                              void* d_out, int out_size, void* d_ws, size_t ws_size,
                              hipStream_t stream) {
    const float* x     = (const float*)d_in[0];
    const int*   ei    = (const int*)d_in[1];
    const int*   eli   = (const int*)d_in[2];
    const float* W_gcn = (const float*)d_in[3];
    const float* b_gcn = (const float*)d_in[4];
    const float* W_lin = (const float*)d_in[5];
    const float* b_lin = (const float*)d_in[6];
    float* out = (float*)d_out;

    // workspace layout
    float* t         = (float*)d_ws;                           // 100k x 16 f32 (6.4 MB)
    float* proj      = t + (size_t)N_NODES * 16;               // 100k x 16 f32 (6.4 MB)
    float* G         = proj + (size_t)N_NODES * 16;            // 129*16 f32
    float* dinv      = G + 129 * 16;                           // 100k f32
    unsigned* bedge  = (unsigned*)(dinv + N_NODES);            // 1.6M u32 (6.4 MB)
    int*   hist      = (int*)(bedge + N_EDGES);                // 782*782 int (2.4 MB)
    int*   btot      = hist + NBUCK * NBLK_E;                  // 782 int
    int*   bbase     = btot + NBUCK;                           // 782 int
    int*   total     = bbase + NBUCK;                          // 1 int

    hipMemsetAsync(total, 0, sizeof(int), stream);

    // histogram + (merged) G/c0 precompute
    k_hist<<<NBLK_E + PREC_BLKS, 256, 0, stream>>>(ei, hist, W_gcn, b_gcn, W_lin, G);
    // per-bucket scan + atomic-ticket bases
    k_scanb<<<NBUCK, 256, 0, stream>>>(hist, btot, bbase, total);
    // partition edges into buckets
    k_part<<<NBLK_E, 256, 0, stream>>>(ei, hist, bbase, bedge);
    // per-bucket degree -> dinv
    k_deg<<<NBUCK, 256, 0, stream>>>(bedge, bbase, btot, dinv);
    // t = dinv * (x @ G)  (fp32, 64B rows)
    k_t<<<N_NODES * 16 / 256, 256, 0, stream>>>(x, G, dinv, t);
    // edge-parallel bucket accumulation -> proj
    k_accum<<<NBUCK, 256, 0, stream>>>(bedge, bbase, btot, t, dinv, G, proj);
    // out = gather-add
    k_link2<<<(N_LABEL * 8 + 255) / 256, 256, 0, stream>>>(eli, proj, b_lin, out);
}

// Round 15
// 118.251 us; speedup vs baseline: 2.2813x; 2.2813x over previous
//
#include <hip/hip_runtime.h>

#define N_NODES 100000
#define N_EDGES 1600000
#define N_LABEL 200000
#define HID 128
#define OUT 5

#define NBUCK 391        // ceil(N_NODES/256)
#define EPB   2048       // edges per partition block
#define NBLK_E 782       // ceil(N_EDGES/EPB)
#define PREC_BLKS 9      // ceil(129*16/256) precomp blocks appended to k_hist

// ---------------------------------------------------------------------------
// Linear network: out[l] = proj[d][0..4] + proj[p][5..9] + b_lin,
//   t[n]    = dinv_n * (x[n] @ G)            (fp32, 16-col padded, 64B row)
//   proj[n] = dinv_n * (sum_{src} t[src] + t[n]) + c0
// with G = W_gcn @ [W_lin_top | W_lin_bot] (128x10), c0 = b_gcn @ W2.
// This is the R11 structure (best measured: 115.6us) + ticket-base scanb
// + precomp merged into hist. R12/R13 (bf16 rows) and R14 (LDS atomics)
// both measured worse and are reverted.
// ---------------------------------------------------------------------------

// K_hist (+ merged precomp): blocks < NBLK_E histogram dst buckets;
// blocks >= NBLK_E compute G (row 128 = c0 = b_gcn @ W2).
__global__ __launch_bounds__(256) void k_hist(const int* __restrict__ ei,
                                              int* __restrict__ hist,
                                              const float* __restrict__ Wg,
                                              const float* __restrict__ bg,
                                              const float* __restrict__ Wl,
                                              float* __restrict__ G) {
    const int t = threadIdx.x, b = blockIdx.x;
    if (b >= NBLK_E) {   // precomp path (whole block)
        int o = (b - NBLK_E) * 256 + t;
        if (o < 129 * 16) {
            int r = o >> 4, jj = o & 15;
            float acc = 0.f;
            if (jj < 2 * OUT) {
                const int half = (jj >= OUT);
                const int j = half ? jj - OUT : jj;
                for (int c = 0; c < HID; ++c) {
                    float w2 = Wl[(half * HID + c) * OUT + j];
                    float a = (r < HID) ? Wg[r * HID + c] : bg[c];
                    acc += a * w2;
                }
            }
            G[o] = acc;
        }
        return;
    }
    __shared__ int h[NBUCK];
    for (int i = t; i < NBUCK; i += 256) h[i] = 0;
    __syncthreads();
    const int e0 = b * EPB;
#pragma unroll
    for (int i = 0; i < 8; ++i) {
        int e = e0 + i * 256 + t;
        if (e < N_EDGES) atomicAdd(&h[ei[N_EDGES + e] >> 8], 1);
    }
    __syncthreads();
    for (int i = t; i < NBUCK; i += 256) hist[i * NBLK_E + b] = h[i];
}

// K_scanb: per-bucket scan over 782 block entries + atomic-ticket bucket base
// (bases disjoint, order irrelevant — no global scan kernel needed).
__global__ __launch_bounds__(256) void k_scanb(int* __restrict__ hist,
                                               int* __restrict__ btot,
                                               int* __restrict__ bbase,
                                               int* __restrict__ total) {
    __shared__ int part[256];
    const int b = blockIdx.x, t = threadIdx.x;
    int* row = hist + b * NBLK_E;
    const int lo = t * 4, hi = min(lo + 4, NBLK_E);
    int v[4]; int s = 0;
    for (int i = lo; i < hi; ++i) { v[i - lo] = row[i]; s += v[i - lo]; }
    part[t] = s;
    __syncthreads();
#pragma unroll
    for (int off = 1; off < 256; off <<= 1) {
        int a = (t >= off) ? part[t - off] : 0;
        __syncthreads();
        part[t] += a;
        __syncthreads();
    }
    int run = part[t] - s;
    for (int i = lo; i < hi; ++i) { int x = v[i - lo]; row[i] = run; run += x; }
    if (t == 255) {
        int tot = part[255];
        btot[b] = tot;
        bbase[b] = atomicAdd(total, tot);   // disjoint range ticket
    }
}

// K_part: partition edges into bucket regions. bedge = src | (dst&255)<<20.
__global__ __launch_bounds__(256) void k_part(const int* __restrict__ ei,
                                              const int* __restrict__ hist,
                                              const int* __restrict__ bbase,
                                              unsigned* __restrict__ bedge) {
    __shared__ int cur[NBUCK];
    const int t = threadIdx.x, b = blockIdx.x;
    for (int i = t; i < NBUCK; i += 256) cur[i] = bbase[i] + hist[i * NBLK_E + b];
    __syncthreads();
    const int e0 = b * EPB;
#pragma unroll
    for (int i = 0; i < 8; ++i) {
        int e = e0 + i * 256 + t;
        if (e < N_EDGES) {
            int dst = ei[N_EDGES + e];
            unsigned src = (unsigned)ei[e];
            int pos = atomicAdd(&cur[dst >> 8], 1);
            bedge[pos] = src | ((unsigned)(dst & 255) << 20);
        }
    }
}

// K_build: per-bucket CSR (LDS count/scan/rank) -> csr, seg, dinv.
__global__ __launch_bounds__(256) void k_build(const unsigned* __restrict__ bedge,
                                               const int* __restrict__ bbase,
                                               const int* __restrict__ btot,
                                               int* __restrict__ csr,
                                               int2* __restrict__ seg,
                                               float* __restrict__ dinv) {
    __shared__ int cnt[256];
    __shared__ int nb[256];
    __shared__ int cursor[256];
    const int b = blockIdx.x, t = threadIdx.x;
    const int base = bbase[b];
    const int size = btot[b];
    cnt[t] = 0;
    __syncthreads();
    for (int i = t; i < size; i += 256) atomicAdd(&cnt[bedge[base + i] >> 20], 1);
    __syncthreads();
    const int c = cnt[t];
    nb[t] = c;
    __syncthreads();
#pragma unroll
    for (int off = 1; off < 256; off <<= 1) {
        int a = (t >= off) ? nb[t - off] : 0;
        __syncthreads();
        nb[t] += a;
        __syncthreads();
    }
    const int myBase = nb[t] - c;
    cursor[t] = myBase;
    __syncthreads();
    for (int i = t; i < size; i += 256) {
        unsigned v = bedge[base + i];
        int pos = atomicAdd(&cursor[v >> 20], 1);
        csr[base + pos] = (int)(v & 0xFFFFFu);
    }
    const int n = b * 256 + t;
    if (n < N_NODES) {
        seg[n] = make_int2(base + myBase, c);
        dinv[n] = rsqrtf((float)(c + 1));
    }
}

// K_t: t[n][0..9] = dinv[n] * (x[n] @ G), rows padded to 16 (cols 10-15 = 0).
//      16 lanes per node; coalesced x loads; G in LDS stride 11 (conflict-free).
__global__ __launch_bounds__(256) void k_t(const float* __restrict__ x,
                                           const float* __restrict__ G,
                                           const float* __restrict__ dinv,
                                           float* __restrict__ t) {
    __shared__ float Gs[HID * 11];
    const int tid = threadIdx.x;
    for (int o = tid; o < HID * 10; o += 256) {
        int k = o / 10, j = o - k * 10;
        Gs[k * 11 + j] = G[k * 16 + j];
    }
    __syncthreads();

    int gid = blockIdx.x * 256 + tid;
    int n = gid >> 4;
    int i = gid & 15;

    float xv[8];
#pragma unroll
    for (int m = 0; m < 8; ++m) xv[m] = x[(size_t)n * HID + i + 16 * m];

    float p[10];
#pragma unroll
    for (int j = 0; j < 10; ++j) p[j] = 0.f;
#pragma unroll
    for (int m = 0; m < 8; ++m) {
        const float* g = &Gs[(i + 16 * m) * 11];
#pragma unroll
        for (int j = 0; j < 10; ++j) p[j] += xv[m] * g[j];
    }
#pragma unroll
    for (int off = 1; off < 16; off <<= 1) {
#pragma unroll
        for (int j = 0; j < 10; ++j) p[j] += __shfl_xor(p[j], off);
    }
    float val = (i == 0) ? p[0] : (i == 1) ? p[1] : (i == 2) ? p[2] : (i == 3) ? p[3] :
                (i == 4) ? p[4] : (i == 5) ? p[5] : (i == 6) ? p[6] : (i == 7) ? p[7] :
                (i == 8) ? p[8] : (i == 9) ? p[9] : 0.f;
    t[(size_t)n * 16 + i] = dinv[n] * val;
}

// K_pullt: proj[n] = dinv[n]*(sum_src t[src] + t[n]) + c0.  (R11 version)
//     16 lanes per node; per edge one 64B line gather; csr loaded 16-wide
//     and shfl-broadcast; 4x unrolled for MLP.
__global__ __launch_bounds__(256) void k_pullt(const float* __restrict__ t,
                                               const int2* __restrict__ seg,
                                               const int* __restrict__ csr,
                                               const float* __restrict__ dinv,
                                               const float* __restrict__ G,
                                               float* __restrict__ proj) {
    int gid = blockIdx.x * 256 + threadIdx.x;
    int n = gid >> 4;
    int i = gid & 15;
    const int gbase = threadIdx.x & 48;   // 16-lane group base within wave

    float acc = t[(size_t)n * 16 + i];    // self term
    const int2 sg = seg[n];
    const int beg = sg.x, deg = sg.y;

    for (int base = 0; base < deg; base += 16) {
        const int cnt = min(16, deg - base);
        int idx = (i < cnt) ? csr[beg + base + i] : 0;
        int j = 0;
        for (; j + 4 <= cnt; j += 4) {
            int s0 = __shfl(idx, gbase + j);
            int s1 = __shfl(idx, gbase + j + 1);
            int s2 = __shfl(idx, gbase + j + 2);
            int s3 = __shfl(idx, gbase + j + 3);
            float v0 = t[(size_t)s0 * 16 + i];
            float v1 = t[(size_t)s1 * 16 + i];
            float v2 = t[(size_t)s2 * 16 + i];
            float v3 = t[(size_t)s3 * 16 + i];
            acc += v0; acc += v1; acc += v2; acc += v3;
        }
        for (; j < cnt; ++j) {
            int s = __shfl(idx, gbase + j);
            acc += t[(size_t)s * 16 + i];
        }
    }
    proj[(size_t)n * 16 + i] = dinv[n] * acc + G[HID * 16 + i];   // + c0
}

// K_link: out[l][o] = proj[d][o] + proj[p][5+o] + b_lin[o]
__global__ __launch_bounds__(256) void k_link2(const int* __restrict__ eli,
                                               const float* __restrict__ proj,
                                               const float* __restrict__ bl,
                                               float* __restrict__ out) {
    int t = blockIdx.x * 256 + threadIdx.x;
    int l = t >> 3, o = t & 7;
    if (l >= N_LABEL || o >= OUT) return;
    int d = eli[l];
    int p = eli[N_LABEL + l];
    out[l * OUT + o] = proj[d * 16 + o] + proj[p * 16 + OUT + o] + bl[o];
}

// ---------------------------------------------------------------------------
extern "C" void kernel_launch(void* const* d_in, const int* in_sizes, int n_in,
                              void* d_out, int out_size, void* d_ws, size_t ws_size,
                              hipStream_t stream) {
    const float* x     = (const float*)d_in[0];
    const int*   ei    = (const int*)d_in[1];
    const int*   eli   = (const int*)d_in[2];
    const float* W_gcn = (const float*)d_in[3];
    const float* b_gcn = (const float*)d_in[4];
    const float* W_lin = (const float*)d_in[5];
    const float* b_lin = (const float*)d_in[6];
    float* out = (float*)d_out;

    // workspace layout
    float* t         = (float*)d_ws;                           // 100k x 16 f32 (6.4 MB)
    float* proj      = t + (size_t)N_NODES * 16;               // 100k x 16 f32 (6.4 MB)
    float* G         = proj + (size_t)N_NODES * 16;            // 129*16 f32
    float* dinv      = G + 129 * 16;                           // 100k f32
    unsigned* bedge  = (unsigned*)(dinv + N_NODES);            // 1.6M u32 (6.4 MB)
    int*   csr       = (int*)(bedge + N_EDGES);                // 1.6M int (6.4 MB)
    int2*  seg       = (int2*)(csr + N_EDGES);                 // 100k int2
    int*   hist      = (int*)(seg + N_NODES);                  // 391*782 int
    int*   btot      = hist + NBUCK * NBLK_E;                  // 391 int
    int*   bbase     = btot + NBUCK;                           // 391 int
    int*   total     = bbase + NBUCK;                          // 1 int

    hipMemsetAsync(total, 0, sizeof(int), stream);

    // histogram + (merged) G/c0 precompute
    k_hist<<<NBLK_E + PREC_BLKS, 256, 0, stream>>>(ei, hist, W_gcn, b_gcn, W_lin, G);
    // per-bucket scan + atomic-ticket bases
    k_scanb<<<NBUCK, 256, 0, stream>>>(hist, btot, bbase, total);
    // partition edges into buckets
    k_part<<<NBLK_E, 256, 0, stream>>>(ei, hist, bbase, bedge);
    // per-bucket CSR + seg + dinv
    k_build<<<NBUCK, 256, 0, stream>>>(bedge, bbase, btot, csr, seg, dinv);
    // t = dinv * (x @ G)  (fp32, 64B rows, L2/L3-resident 6.4 MB)
    k_t<<<N_NODES * 16 / 256, 256, 0, stream>>>(x, G, dinv, t);
    // proj = dinv * (sum t[src] + t[n]) + c0
    k_pullt<<<N_NODES * 16 / 256, 256, 0, stream>>>(t, seg, csr, dinv, G, proj);
    // out = gather-add
    k_link2<<<(N_LABEL * 8 + 255) / 256, 256, 0, stream>>>(eli, proj, b_lin, out);
}

// Round 16
// 106.441 us; speedup vs baseline: 2.5345x; 1.1110x over previous
//
#include <hip/hip_runtime.h>

#define N_NODES 100000
#define N_EDGES 1600000
#define N_LABEL 200000
#define HID 128
#define OUT 5

#define NBUCK 391        // ceil(N_NODES/256) node buckets
#define EPB   4096       // edges per partition block (R16: was 2048)
#define NBLK_E 391       // ceil(N_EDGES/EPB)
#define PREC_BLKS 9      // ceil(129*16/256) precomp blocks appended to k_hist

// ---------------------------------------------------------------------------
// Linear network: out[l] = proj[d][0..4] + proj[p][5..9] + b_lin,
//   t[n]    = dinv_n * (x[n] @ G)            (fp32, 16-col padded, 64B row)
//   proj[n] = dinv_n * (sum_{src} t[src] + t[n]) + c0
// with G = W_gcn @ [W_lin_top | W_lin_bot] (128x10), c0 = b_gcn @ W2.
// Base = R11/R15 measured-good structure; R16 = denser partition blocks,
// memset folded into k_hist, dense link mapping.
// ---------------------------------------------------------------------------

// K_hist (+ merged precomp): blocks < NBLK_E histogram dst buckets;
// blocks >= NBLK_E compute G (row 128 = c0 = b_gcn @ W2); also total=0.
__global__ __launch_bounds__(256) void k_hist(const int* __restrict__ ei,
                                              int* __restrict__ hist,
                                              const float* __restrict__ Wg,
                                              const float* __restrict__ bg,
                                              const float* __restrict__ Wl,
                                              float* __restrict__ G,
                                              int* __restrict__ total) {
    const int t = threadIdx.x, b = blockIdx.x;
    if (b >= NBLK_E) {   // precomp path (whole block)
        if (b == NBLK_E && t == 0) *total = 0;   // ticket counter reset
        int o = (b - NBLK_E) * 256 + t;
        if (o < 129 * 16) {
            int r = o >> 4, jj = o & 15;
            float acc = 0.f;
            if (jj < 2 * OUT) {
                const int half = (jj >= OUT);
                const int j = half ? jj - OUT : jj;
                for (int c = 0; c < HID; ++c) {
                    float w2 = Wl[(half * HID + c) * OUT + j];
                    float a = (r < HID) ? Wg[r * HID + c] : bg[c];
                    acc += a * w2;
                }
            }
            G[o] = acc;
        }
        return;
    }
    __shared__ int h[NBUCK];
    for (int i = t; i < NBUCK; i += 256) h[i] = 0;
    __syncthreads();
    const int e0 = b * EPB;
#pragma unroll
    for (int i = 0; i < 16; ++i) {
        int e = e0 + i * 256 + t;
        if (e < N_EDGES) atomicAdd(&h[ei[N_EDGES + e] >> 8], 1);
    }
    __syncthreads();
    for (int i = t; i < NBUCK; i += 256) hist[i * NBLK_E + b] = h[i];
}

// K_scanb: per-bucket scan over 391 block entries + atomic-ticket bucket base.
__global__ __launch_bounds__(256) void k_scanb(int* __restrict__ hist,
                                               int* __restrict__ btot,
                                               int* __restrict__ bbase,
                                               int* __restrict__ total) {
    __shared__ int part[256];
    const int b = blockIdx.x, t = threadIdx.x;
    int* row = hist + b * NBLK_E;
    const int lo = t * 2, hi = min(lo + 2, NBLK_E);
    int v[2]; int s = 0;
    for (int i = lo; i < hi; ++i) { v[i - lo] = row[i]; s += v[i - lo]; }
    part[t] = s;
    __syncthreads();
#pragma unroll
    for (int off = 1; off < 256; off <<= 1) {
        int a = (t >= off) ? part[t - off] : 0;
        __syncthreads();
        part[t] += a;
        __syncthreads();
    }
    int run = part[t] - s;
    for (int i = lo; i < hi; ++i) { int x = v[i - lo]; row[i] = run; run += x; }
    if (t == 255) {
        int tot = part[255];
        btot[b] = tot;
        bbase[b] = atomicAdd(total, tot);   // disjoint range ticket
    }
}

// K_part: partition edges into bucket regions. bedge = src | (dst&255)<<20.
__global__ __launch_bounds__(256) void k_part(const int* __restrict__ ei,
                                              const int* __restrict__ hist,
                                              const int* __restrict__ bbase,
                                              unsigned* __restrict__ bedge) {
    __shared__ int cur[NBUCK];
    const int t = threadIdx.x, b = blockIdx.x;
    for (int i = t; i < NBUCK; i += 256) cur[i] = bbase[i] + hist[i * NBLK_E + b];
    __syncthreads();
    const int e0 = b * EPB;
#pragma unroll
    for (int i = 0; i < 16; ++i) {
        int e = e0 + i * 256 + t;
        if (e < N_EDGES) {
            int dst = ei[N_EDGES + e];
            unsigned src = (unsigned)ei[e];
            int pos = atomicAdd(&cur[dst >> 8], 1);
            bedge[pos] = src | ((unsigned)(dst & 255) << 20);
        }
    }
}

// K_build: per-bucket CSR (LDS count/scan/rank) -> csr, seg, dinv.
__global__ __launch_bounds__(256) void k_build(const unsigned* __restrict__ bedge,
                                               const int* __restrict__ bbase,
                                               const int* __restrict__ btot,
                                               int* __restrict__ csr,
                                               int2* __restrict__ seg,
                                               float* __restrict__ dinv) {
    __shared__ int cnt[256];
    __shared__ int nb[256];
    __shared__ int cursor[256];
    const int b = blockIdx.x, t = threadIdx.x;
    const int base = bbase[b];
    const int size = btot[b];
    cnt[t] = 0;
    __syncthreads();
    for (int i = t; i < size; i += 256) atomicAdd(&cnt[bedge[base + i] >> 20], 1);
    __syncthreads();
    const int c = cnt[t];
    nb[t] = c;
    __syncthreads();
#pragma unroll
    for (int off = 1; off < 256; off <<= 1) {
        int a = (t >= off) ? nb[t - off] : 0;
        __syncthreads();
        nb[t] += a;
        __syncthreads();
    }
    const int myBase = nb[t] - c;
    cursor[t] = myBase;
    __syncthreads();
    for (int i = t; i < size; i += 256) {
        unsigned v = bedge[base + i];
        int pos = atomicAdd(&cursor[v >> 20], 1);
        csr[base + pos] = (int)(v & 0xFFFFFu);
    }
    const int n = b * 256 + t;
    if (n < N_NODES) {
        seg[n] = make_int2(base + myBase, c);
        dinv[n] = rsqrtf((float)(c + 1));
    }
}

// K_t: t[n][0..9] = dinv[n] * (x[n] @ G), rows padded to 16 (cols 10-15 = 0).
__global__ __launch_bounds__(256) void k_t(const float* __restrict__ x,
                                           const float* __restrict__ G,
                                           const float* __restrict__ dinv,
                                           float* __restrict__ t) {
    __shared__ float Gs[HID * 11];
    const int tid = threadIdx.x;
    for (int o = tid; o < HID * 10; o += 256) {
        int k = o / 10, j = o - k * 10;
        Gs[k * 11 + j] = G[k * 16 + j];
    }
    __syncthreads();

    int gid = blockIdx.x * 256 + tid;
    int n = gid >> 4;
    int i = gid & 15;

    float xv[8];
#pragma unroll
    for (int m = 0; m < 8; ++m) xv[m] = x[(size_t)n * HID + i + 16 * m];

    float p[10];
#pragma unroll
    for (int j = 0; j < 10; ++j) p[j] = 0.f;
#pragma unroll
    for (int m = 0; m < 8; ++m) {
        const float* g = &Gs[(i + 16 * m) * 11];
#pragma unroll
        for (int j = 0; j < 10; ++j) p[j] += xv[m] * g[j];
    }
#pragma unroll
    for (int off = 1; off < 16; off <<= 1) {
#pragma unroll
        for (int j = 0; j < 10; ++j) p[j] += __shfl_xor(p[j], off);
    }
    float val = (i == 0) ? p[0] : (i == 1) ? p[1] : (i == 2) ? p[2] : (i == 3) ? p[3] :
                (i == 4) ? p[4] : (i == 5) ? p[5] : (i == 6) ? p[6] : (i == 7) ? p[7] :
                (i == 8) ? p[8] : (i == 9) ? p[9] : 0.f;
    t[(size_t)n * 16 + i] = dinv[n] * val;
}

// K_pullt: proj[n] = dinv[n]*(sum_src t[src] + t[n]) + c0.  (R11 version)
__global__ __launch_bounds__(256) void k_pullt(const float* __restrict__ t,
                                               const int2* __restrict__ seg,
                                               const int* __restrict__ csr,
                                               const float* __restrict__ dinv,
                                               const float* __restrict__ G,
                                               float* __restrict__ proj) {
    int gid = blockIdx.x * 256 + threadIdx.x;
    int n = gid >> 4;
    int i = gid & 15;
    const int gbase = threadIdx.x & 48;   // 16-lane group base within wave

    float acc = t[(size_t)n * 16 + i];    // self term
    const int2 sg = seg[n];
    const int beg = sg.x, deg = sg.y;

    for (int base = 0; base < deg; base += 16) {
        const int cnt = min(16, deg - base);
        int idx = (i < cnt) ? csr[beg + base + i] : 0;
        int j = 0;
        for (; j + 4 <= cnt; j += 4) {
            int s0 = __shfl(idx, gbase + j);
            int s1 = __shfl(idx, gbase + j + 1);
            int s2 = __shfl(idx, gbase + j + 2);
            int s3 = __shfl(idx, gbase + j + 3);
            float v0 = t[(size_t)s0 * 16 + i];
            float v1 = t[(size_t)s1 * 16 + i];
            float v2 = t[(size_t)s2 * 16 + i];
            float v3 = t[(size_t)s3 * 16 + i];
            acc += v0; acc += v1; acc += v2; acc += v3;
        }
        for (; j < cnt; ++j) {
            int s = __shfl(idx, gbase + j);
            acc += t[(size_t)s * 16 + i];
        }
    }
    proj[(size_t)n * 16 + i] = dinv[n] * acc + G[HID * 16 + i];   // + c0
}

// K_link: dense mapping — one thread per output element.
//   idx = l*5 + o; out[idx] = proj[d][o] + proj[p][5+o] + b_lin[o]
__global__ __launch_bounds__(256) void k_link2(const int* __restrict__ eli,
                                               const float* __restrict__ proj,
                                               const float* __restrict__ bl,
                                               float* __restrict__ out) {
    int idx = blockIdx.x * 256 + threadIdx.x;
    if (idx >= N_LABEL * OUT) return;
    int l = idx / OUT;
    int o = idx - l * OUT;
    int d = eli[l];
    int p = eli[N_LABEL + l];
    out[idx] = proj[d * 16 + o] + proj[p * 16 + OUT + o] + bl[o];
}

// ---------------------------------------------------------------------------
extern "C" void kernel_launch(void* const* d_in, const int* in_sizes, int n_in,
                              void* d_out, int out_size, void* d_ws, size_t ws_size,
                              hipStream_t stream) {
    const float* x     = (const float*)d_in[0];
    const int*   ei    = (const int*)d_in[1];
    const int*   eli   = (const int*)d_in[2];
    const float* W_gcn = (const float*)d_in[3];
    const float* b_gcn = (const float*)d_in[4];
    const float* W_lin = (const float*)d_in[5];
    const float* b_lin = (const float*)d_in[6];
    float* out = (float*)d_out;

    // workspace layout
    float* t         = (float*)d_ws;                           // 100k x 16 f32 (6.4 MB)
    float* proj      = t + (size_t)N_NODES * 16;               // 100k x 16 f32 (6.4 MB)
    float* G         = proj + (size_t)N_NODES * 16;            // 129*16 f32
    float* dinv      = G + 129 * 16;                           // 100k f32
    unsigned* bedge  = (unsigned*)(dinv + N_NODES);            // 1.6M u32 (6.4 MB)
    int*   csr       = (int*)(bedge + N_EDGES);                // 1.6M int (6.4 MB)
    int2*  seg       = (int2*)(csr + N_EDGES);                 // 100k int2
    int*   hist      = (int*)(seg + N_NODES);                  // 391*391 int (0.6 MB)
    int*   btot      = hist + NBUCK * NBLK_E;                  // 391 int
    int*   bbase     = btot + NBUCK;                           // 391 int
    int*   total     = bbase + NBUCK;                          // 1 int

    // histogram + (merged) G/c0 precompute + total reset
    k_hist<<<NBLK_E + PREC_BLKS, 256, 0, stream>>>(ei, hist, W_gcn, b_gcn, W_lin, G, total);
    // per-bucket scan + atomic-ticket bases
    k_scanb<<<NBUCK, 256, 0, stream>>>(hist, btot, bbase, total);
    // partition edges into buckets (denser blocks: EPB=4096)
    k_part<<<NBLK_E, 256, 0, stream>>>(ei, hist, bbase, bedge);
    // per-bucket CSR + seg + dinv
    k_build<<<NBUCK, 256, 0, stream>>>(bedge, bbase, btot, csr, seg, dinv);
    // t = dinv * (x @ G)
    k_t<<<N_NODES * 16 / 256, 256, 0, stream>>>(x, G, dinv, t);
    // proj = dinv * (sum t[src] + t[n]) + c0
    k_pullt<<<N_NODES * 16 / 256, 256, 0, stream>>>(t, seg, csr, dinv, G, proj);
    // out = gather-add (dense mapping)
    k_link2<<<(N_LABEL * OUT + 255) / 256, 256, 0, stream>>>(eli, proj, b_lin, out);
}